// Round 7
// baseline (1039.029 us; speedup 1.0000x reference)
//
#include <hip/hip_runtime.h>
#include <hip/hip_bf16.h>
#include <stdint.h>

#define VOCAB 30000
#define EMBED 256
#define HID   128
#define BB    256
#define TT    512
#define G4    (4*HID)    // 512 gate columns per direction
#define GW    (2*G4)     // 1024 columns in embW (fw | bw)
#define BPB   16         // batches per lstm block (fills the MFMA M dim)

typedef _Float16 f16x8 __attribute__((ext_vector_type(8)));
typedef float    f32x4 __attribute__((ext_vector_type(4)));

__device__ __forceinline__ float sigm(float x){
  return 1.0f / (1.0f + __expf(-x));
}
__device__ __forceinline__ float fast_tanh(float x){
  float e = __expf(2.0f * x);
  return 1.0f - 2.0f / (e + 1.0f);
}

// ---------------------------------------------------------------------------
// Kernel 1: EW[v][g] = emb[v][:] @ [Wf|Wb][:,g] + bias[g]   via MFMA f16.
// ---------------------------------------------------------------------------
__global__ __launch_bounds__(256, 4) void embw_mfma(
    const float* __restrict__ emb,
    const float* __restrict__ Wf, const float* __restrict__ Wb,
    const float* __restrict__ bf, const float* __restrict__ bb,
    float* __restrict__ EW)
{
  __shared__ _Float16 As[64*EMBED];   // 32 KB
  const int tid = threadIdx.x;
  const int l   = tid & 63;
  const int w   = tid >> 6;
  const int r0  = blockIdx.x * 64;
  const int c0  = blockIdx.y * 64;
  const int nr  = min(64, VOCAB - r0);

  const float4* asrc = (const float4*)(emb + (size_t)r0*EMBED);
  for (int i = tid; i < nr*(EMBED/4); i += 256){
    float4 v = asrc[i];
    const int row = i >> 6;
    const int kc  = (i & 63) * 4;
    const int ks  = kc ^ ((row & 7) << 3);
    _Float16* dst = &As[row*EMBED + ks];
    dst[0]=(_Float16)v.x; dst[1]=(_Float16)v.y;
    dst[2]=(_Float16)v.z; dst[3]=(_Float16)v.w;
  }
  __syncthreads();

  const int cl = w*16 + (l & 15);
  const int cg = c0 + cl;
  const float* Wsrc = (cg < G4) ? (Wf + cg) : (Wb + (cg - G4));
  const int kg = (l >> 4) * 8;

  f32x4 acc[4] = {{0,0,0,0},{0,0,0,0},{0,0,0,0},{0,0,0,0}};

  for (int kk = 0; kk < EMBED/32; ++kk){
    const int kb = kk*32 + kg;
    f16x8 bfrag;
    #pragma unroll
    for (int j = 0; j < 8; ++j)
      bfrag[j] = (_Float16)Wsrc[(size_t)(kb + j)*G4];
    #pragma unroll
    for (int m = 0; m < 4; ++m){
      const int row = m*16 + (l & 15);
      const int ks  = kb ^ ((row & 7) << 3);
      f16x8 afrag = *(const f16x8*)&As[row*EMBED + ks];
      acc[m] = __builtin_amdgcn_mfma_f32_16x16x32_f16(afrag, bfrag, acc[m], 0, 0, 0);
    }
  }

  const float bv = (cg < G4) ? bf[cg] : bb[cg - G4];
  #pragma unroll
  for (int m = 0; m < 4; ++m){
    #pragma unroll
    for (int r = 0; r < 4; ++r){
      const int vrow = r0 + m*16 + (l >> 4)*4 + r;
      if (vrow < VOCAB)
        EW[(size_t)vrow*GW + cg] = acc[m][r] + bv;
    }
  }
}

// ---------------------------------------------------------------------------
// Kernel 2: recurrence, 16 batches per block (full MFMA M-dim). Grid = 32.
// 8 waves; wave w owns ucols [w*16, w*16+16) x 4 gates (B-frags resident).
// A = h[16 batches][128] from swizzled dbuf LDS; D row = batch = hi*4+r,
// col = ucol = w*16+lr -> lane natively holds z[i,f,g,o] for 4 (batch,unit)
// pairs: gates on ALL 64 lanes, no cross-lane redistribution, 1 barrier/step.
// ---------------------------------------------------------------------------
__global__ __launch_bounds__(512, 2) void lstm16(
    const int*   __restrict__ tokens,
    const float* __restrict__ EW,
    const float* __restrict__ Ufw, const float* __restrict__ Ubw,
    float* __restrict__ out)
{
  __shared__ _Float16 h_lds[2][16*HID];   // 2 x 4 KB, XOR-swizzled 16B chunks
  __shared__ int      tok_lds[BPB*TT];    // 32 KB

  const int tid = threadIdx.x;
  const int l   = tid & 63;
  const int w   = tid >> 6;               // wave 0..7
  const int lr  = l & 15;                 // A row = batch-col of D? no: D col = ucol offset
  const int hi  = l >> 4;
  const int dir = blockIdx.x & 1;
  const int b0  = (blockIdx.x >> 1) * BPB;

  for (int i = tid; i < 2*16*HID; i += 512) ((_Float16*)h_lds)[i] = (_Float16)0.f;
  for (int i = tid; i < BPB*TT; i += 512)
    tok_lds[i] = tokens[(b0 + (i >> 9))*TT + (i & 511)];
  __syncthreads();

  // ---- resident U B-fragments: ub[kt][gate], 64 VGPRs ----
  // B[k][n]: lane col n = lr -> ucol = w*16+lr ; k = kt*32 + hi*8 + j
  const float* U = dir ? Ubw : Ufw;
  f16x8 ub[4][4];
  #pragma unroll
  for (int kt = 0; kt < 4; ++kt){
    #pragma unroll
    for (int g = 0; g < 4; ++g){
      const int col = g*128 + w*16 + lr;
      f16x8 f;
      #pragma unroll
      for (int j = 0; j < 8; ++j)
        f[j] = (_Float16)U[(size_t)(kt*32 + hi*8 + j)*G4 + col];
      ub[kt][g] = f;
    }
  }

  const int gcol = w*16 + lr;             // this lane's hidden unit
  f32x4 creg = {0.f,0.f,0.f,0.f};
  float hfin[4] = {0.f,0.f,0.f,0.f};

  // ---- xw for step 0: xwc[g][r] = EW[tok[b=hi*4+r][t0]][dir*G4+g*128+gcol]
  f32x4 xwc[4], xwn[4];
  {
    const int t0 = dir ? (TT-1) : 0;
    #pragma unroll
    for (int r = 0; r < 4; ++r){
      const int tk = tok_lds[(hi*4+r)*TT + t0];
      const float* src = EW + (size_t)tk*GW + dir*G4 + gcol;
      #pragma unroll
      for (int g = 0; g < 4; ++g) xwc[g][r] = src[g*128];
    }
  }

  for (int s = 0; s < TT; ++s){
    const int t   = dir ? (TT-1-s) : s;
    const int cur = s & 1, nxt = cur ^ 1;

    // ---- A-fragments: h[batch=lr][k], swizzled chunks ----
    f16x8 ha[4];
    #pragma unroll
    for (int kt = 0; kt < 4; ++kt){
      const int chunk = (kt*4 + hi) ^ (lr & 7);
      ha[kt] = *(const f16x8*)((const char*)h_lds[cur] + lr*256 + chunk*16);
    }

    // ---- prefetch xw for step s+1 (in flight across the barrier) ----
    {
      int sn = s + 1; sn = sn < TT ? sn : TT-1;
      const int tn = dir ? (TT-1-sn) : sn;
      #pragma unroll
      for (int r = 0; r < 4; ++r){
        const int tk = tok_lds[(hi*4+r)*TT + tn];
        const float* src = EW + (size_t)tk*GW + dir*G4 + gcol;
        #pragma unroll
        for (int g = 0; g < 4; ++g) xwn[g][r] = src[g*128];
      }
    }

    // ---- MFMA: z = xw + h @ U ; acc[g][r] = z[batch hi*4+r][gate g] ----
    f32x4 acc[4];
    #pragma unroll
    for (int g = 0; g < 4; ++g) acc[g] = xwc[g];
    #pragma unroll
    for (int kt = 0; kt < 4; ++kt){
      #pragma unroll
      for (int g = 0; g < 4; ++g)
        acc[g] = __builtin_amdgcn_mfma_f32_16x16x32_f16(ha[kt], ub[kt][g], acc[g], 0, 0, 0);
    }

    // ---- gates: all 64 lanes, 4 (batch,unit) pairs each ----
    #pragma unroll
    for (int r = 0; r < 4; ++r){
      const float zi = acc[0][r], zf = acc[1][r];
      const float zg = acc[2][r], zo = acc[3][r];
      const float cn = sigm(zf)*creg[r] + sigm(zi)*fast_tanh(zg);
      creg[r] = cn;
      const float hh = sigm(zo)*fast_tanh(cn);
      hfin[r] = hh;
      const int row = hi*4 + r;
      const int byte = row*256 + ((((gcol >> 3) ^ (row & 7)) & 15) << 4) + (gcol & 7)*2;
      *(_Float16*)((char*)h_lds[nxt] + byte) = (_Float16)hh;
      out[((size_t)(b0+row)*TT + t)*(2*HID) + (size_t)dir*HID + gcol] = hh;
    }

    asm volatile("s_waitcnt lgkmcnt(0)" ::: "memory");
    __builtin_amdgcn_s_barrier();

    #pragma unroll
    for (int g = 0; g < 4; ++g) xwc[g] = xwn[g];
  }

  // ---- final h_T / c_T ----
  {
    const size_t O1 = (size_t)BB*TT*(2*HID);
    #pragma unroll
    for (int r = 0; r < 4; ++r){
      const size_t idx = (size_t)(b0 + hi*4 + r)*HID + gcol;
      if (dir == 0){
        out[O1                    + idx] = hfin[r];
        out[O1 +   (size_t)BB*HID + idx] = creg[r];
      } else {
        out[O1 + 2*(size_t)BB*HID + idx] = hfin[r];
        out[O1 + 3*(size_t)BB*HID + idx] = creg[r];
      }
    }
  }
}

extern "C" void kernel_launch(void* const* d_in, const int* in_sizes, int n_in,
                              void* d_out, int out_size, void* d_ws, size_t ws_size,
                              hipStream_t stream)
{
  const int*   tokens = (const int*)  d_in[0];
  const float* emb    = (const float*)d_in[1];
  const float* Wf     = (const float*)d_in[2];
  const float* Ufw    = (const float*)d_in[3];
  const float* bf     = (const float*)d_in[4];
  const float* Wb     = (const float*)d_in[5];
  const float* Ubw    = (const float*)d_in[6];
  const float* bb     = (const float*)d_in[7];
  float* out = (float*)d_out;
  float* EW  = (float*)d_ws;          // 30000 x 1024 f32 = 122.88 MB

  embw_mfma<<<dim3((VOCAB + 63)/64, GW/64), 256, 0, stream>>>(emb, Wf, Wb, bf, bb, EW);
  lstm16<<<(BB/BPB)*2, 512, 0, stream>>>(tokens, EW, Ufw, Ubw, out);
}

// Round 8
// 409.491 us; speedup vs baseline: 2.5374x; 2.5374x over previous
//
#include <hip/hip_runtime.h>
#include <hip/hip_bf16.h>
#include <stdint.h>

#define VOCAB 30000
#define EMBED 256
#define HID   128
#define BB    256
#define TT    512
#define G4    (4*HID)    // 512 gate columns per direction
#define GW    (2*G4)     // 1024 columns in embW (fw | bw)
#define BPB   2          // batches per lstm block

typedef _Float16 f16x8 __attribute__((ext_vector_type(8)));
typedef float    f32x4 __attribute__((ext_vector_type(4)));

__device__ __forceinline__ float fexp2(float x){
#if __has_builtin(__builtin_amdgcn_exp2f)
  return __builtin_amdgcn_exp2f(x);
#else
  return exp2f(x);
#endif
}
__device__ __forceinline__ float frcp(float x){
#if __has_builtin(__builtin_amdgcn_rcpf)
  return __builtin_amdgcn_rcpf(x);
#else
  return 1.0f/x;
#endif
}
// sigmoid(x) = 1/(1+2^(-x*log2e))          (~4 instr, no IEEE div)
__device__ __forceinline__ float sigm(float x){
  return frcp(1.0f + fexp2(-1.4426950408889634f*x));
}
// tanh(x) = 1 - 2/(2^(2x*log2e)+1)
__device__ __forceinline__ float fast_tanh(float x){
  return 1.0f - 2.0f*frcp(1.0f + fexp2(2.8853900817779268f*x));
}

// ---------------------------------------------------------------------------
// Kernel 1: EW[v][g] = emb[v][:] @ [Wf|Wb][:,g] + bias[g]   via MFMA f16.
// ---------------------------------------------------------------------------
__global__ __launch_bounds__(256, 4) void embw_mfma(
    const float* __restrict__ emb,
    const float* __restrict__ Wf, const float* __restrict__ Wb,
    const float* __restrict__ bf, const float* __restrict__ bb,
    float* __restrict__ EW)
{
  __shared__ _Float16 As[64*EMBED];   // 32 KB
  const int tid = threadIdx.x;
  const int l   = tid & 63;
  const int w   = tid >> 6;
  const int r0  = blockIdx.x * 64;
  const int c0  = blockIdx.y * 64;
  const int nr  = min(64, VOCAB - r0);

  const float4* asrc = (const float4*)(emb + (size_t)r0*EMBED);
  for (int i = tid; i < nr*(EMBED/4); i += 256){
    float4 v = asrc[i];
    const int row = i >> 6;
    const int kc  = (i & 63) * 4;
    const int ks  = kc ^ ((row & 7) << 3);
    _Float16* dst = &As[row*EMBED + ks];
    dst[0]=(_Float16)v.x; dst[1]=(_Float16)v.y;
    dst[2]=(_Float16)v.z; dst[3]=(_Float16)v.w;
  }
  __syncthreads();

  const int cl = w*16 + (l & 15);
  const int cg = c0 + cl;
  const float* Wsrc = (cg < G4) ? (Wf + cg) : (Wb + (cg - G4));
  const int kg = (l >> 4) * 8;

  f32x4 acc[4] = {{0,0,0,0},{0,0,0,0},{0,0,0,0},{0,0,0,0}};

  for (int kk = 0; kk < EMBED/32; ++kk){
    const int kb = kk*32 + kg;
    f16x8 bfrag;
    #pragma unroll
    for (int j = 0; j < 8; ++j)
      bfrag[j] = (_Float16)Wsrc[(size_t)(kb + j)*G4];
    #pragma unroll
    for (int m = 0; m < 4; ++m){
      const int row = m*16 + (l & 15);
      const int ks  = kb ^ ((row & 7) << 3);
      f16x8 afrag = *(const f16x8*)&As[row*EMBED + ks];
      acc[m] = __builtin_amdgcn_mfma_f32_16x16x32_f16(afrag, bfrag, acc[m], 0, 0, 0);
    }
  }

  const float bv = (cg < G4) ? bf[cg] : bb[cg - G4];
  #pragma unroll
  for (int m = 0; m < 4; ++m){
    #pragma unroll
    for (int r = 0; r < 4; ++r){
      const int vrow = r0 + m*16 + (l >> 4)*4 + r;
      if (vrow < VOCAB)
        EW[(size_t)vrow*GW + cg] = acc[m][r] + bv;
    }
  }
}

// ---------------------------------------------------------------------------
// Kernel 2: recurrence. One block = 2 batches x 1 dir (grid 256, full GPU).
// 8 waves; wave w owns ucols [w*16, w*16+16) x 4 gates (U resident, 64 VGPR).
// Batch 0 -> D row 0, batch 1 -> D row 4: z lands in acc[g][0] of lanes 0-15
// (batch 0) and 16-31 (batch 1) -> gates on 32 lanes, 1 unit/lane, NO
// cross-lane moves. h = 2x512B dbuf LDS, broadcast reads. 1 barrier/step.
// Activations use v_exp/v_rcp (no IEEE-div sequences).
// ---------------------------------------------------------------------------
__global__ __launch_bounds__(512, 2) void lstm_r8(
    const int*   __restrict__ tokens,
    const float* __restrict__ EW,
    const float* __restrict__ Ufw, const float* __restrict__ Ubw,
    float* __restrict__ out)
{
  __shared__ _Float16 h_lds[2][2*HID];    // double buffer, 512 B each
  __shared__ int      tok_lds[BPB*TT];    // 4 KB

  const int tid = threadIdx.x;
  const int l   = tid & 63;
  const int w   = tid >> 6;               // wave 0..7
  const int lr  = l & 15;
  const int hi  = l >> 4;
  const int dir = blockIdx.x & 1;
  const int b0  = (blockIdx.x >> 1) * BPB;

  if (tid < 2*2*HID) ((_Float16*)h_lds)[tid] = (_Float16)0.f;
  for (int i = tid; i < BPB*TT; i += 512)
    tok_lds[i] = tokens[(b0 + (i >> 9))*TT + (i & 511)];
  __syncthreads();

  // ---- resident U B-fragments: ub[kt][gate], 64 VGPRs ----
  // B[k][n]: lane col n = lr -> ucol = w*16+lr ; k = kt*32 + hi*8 + j
  const float* U = dir ? Ubw : Ufw;
  f16x8 ub[4][4];
  #pragma unroll
  for (int kt = 0; kt < 4; ++kt){
    #pragma unroll
    for (int g = 0; g < 4; ++g){
      const int col = g*128 + w*16 + lr;
      f16x8 f;
      #pragma unroll
      for (int j = 0; j < 8; ++j)
        f[j] = (_Float16)U[(size_t)(kt*32 + hi*8 + j)*G4 + col];
      ub[kt][g] = f;
    }
  }

  // A-frag h source: row l&15 -> batch_sel (rows 0->b0, 4->b1; others don't-care)
  const int bsel = (l >> 2) & 1;
  // gate identity: lanes 0..31, batch q = hi, unit u = w*16+lr
  const bool act = (l < 32);
  const int  q   = hi & 1;
  const int  u   = w*16 + lr;

  float creg = 0.f, hfin = 0.f;
  float xwc[4], xwn[4];

  // ---- prologue: xw for step 0, address for step 1 ----
  const float* e_next = EW;
  #pragma unroll
  for (int g = 0; g < 4; ++g) xwc[g] = 0.f;
  if (act){
    const int t0 = dir ? (TT-1) : 0;
    const float* e0 = EW + (size_t)tok_lds[q*TT + t0]*GW + dir*G4 + u;
    #pragma unroll
    for (int g = 0; g < 4; ++g) xwc[g] = e0[g*128];
    const int t1 = dir ? (TT-2) : 1;
    e_next = EW + (size_t)tok_lds[q*TT + t1]*GW + dir*G4 + u;
  }

  for (int s = 0; s < TT; ++s){
    const int t   = dir ? (TT-1-s) : s;
    const int cur = s & 1, nxt = cur ^ 1;

    // 1. issue xw loads for step s+1 (addresses ready, zero deps)
    #pragma unroll
    for (int g = 0; g < 4; ++g) xwn[g] = 0.f;
    if (act){
      #pragma unroll
      for (int g = 0; g < 4; ++g) xwn[g] = e_next[g*128];
    }
    // 2. precompute address for step s+2 (off critical path)
    if (act){
      int sn = s + 2; sn = sn < TT ? sn : TT-1;
      const int t2 = dir ? (TT-1-sn) : sn;
      e_next = EW + (size_t)tok_lds[q*TT + t2]*GW + dir*G4 + u;
    }

    // 3. A-fragments: broadcast reads of the 512B h buffer
    f16x8 ha[4];
    #pragma unroll
    for (int kt = 0; kt < 4; ++kt)
      ha[kt] = *(const f16x8*)((const char*)h_lds[cur] + bsel*256 + kt*64 + hi*16);

    // 4. MFMA: z = xw + h @ U ; batch0 in D row 0, batch1 in D row 4
    f32x4 acc[4];
    #pragma unroll
    for (int g = 0; g < 4; ++g) acc[g] = (f32x4){xwc[g], 0.f, 0.f, 0.f};
    #pragma unroll
    for (int kt = 0; kt < 4; ++kt){
      #pragma unroll
      for (int g = 0; g < 4; ++g)
        acc[g] = __builtin_amdgcn_mfma_f32_16x16x32_f16(ha[kt], ub[kt][g], acc[g], 0, 0, 0);
    }

    // 5. gates: lanes 0-31, one (batch,unit) each; z[g] = acc[g][0]
    if (act){
      const float zi = acc[0][0], zf = acc[1][0];
      const float zg = acc[2][0], zo = acc[3][0];
      const float cn = sigm(zf)*creg + sigm(zi)*fast_tanh(zg);
      creg = cn;
      const float hh = sigm(zo)*fast_tanh(cn);
      hfin = hh;
      *(_Float16*)((char*)h_lds[nxt] + q*256 + u*2) = (_Float16)hh;
      out[((size_t)(b0+q)*TT + t)*(2*HID) + (size_t)dir*HID + u] = hh;
    }

    asm volatile("s_waitcnt lgkmcnt(0)" ::: "memory");
    __builtin_amdgcn_s_barrier();

    #pragma unroll
    for (int g = 0; g < 4; ++g) xwc[g] = xwn[g];
  }

  // ---- final h_T / c_T ----
  if (act){
    const size_t O1  = (size_t)BB*TT*(2*HID);
    const size_t idx = (size_t)(b0+q)*HID + u;
    if (dir == 0){
      out[O1                    + idx] = hfin;
      out[O1 +   (size_t)BB*HID + idx] = creg;
    } else {
      out[O1 + 2*(size_t)BB*HID + idx] = hfin;
      out[O1 + 3*(size_t)BB*HID + idx] = creg;
    }
  }
}

extern "C" void kernel_launch(void* const* d_in, const int* in_sizes, int n_in,
                              void* d_out, int out_size, void* d_ws, size_t ws_size,
                              hipStream_t stream)
{
  const int*   tokens = (const int*)  d_in[0];
  const float* emb    = (const float*)d_in[1];
  const float* Wf     = (const float*)d_in[2];
  const float* Ufw    = (const float*)d_in[3];
  const float* bf     = (const float*)d_in[4];
  const float* Wb     = (const float*)d_in[5];
  const float* Ubw    = (const float*)d_in[6];
  const float* bb     = (const float*)d_in[7];
  float* out = (float*)d_out;
  float* EW  = (float*)d_ws;          // 30000 x 1024 f32 = 122.88 MB

  embw_mfma<<<dim3((VOCAB + 63)/64, GW/64), 256, 0, stream>>>(emb, Wf, Wb, bf, bb, EW);
  lstm_r8<<<(BB/BPB)*2, 512, 0, stream>>>(tokens, EW, Ufw, Ubw, out);
}

// Round 9
// 380.562 us; speedup vs baseline: 2.7302x; 1.0760x over previous
//
#include <hip/hip_runtime.h>
#include <hip/hip_bf16.h>
#include <stdint.h>

#define VOCAB 30000
#define EMBED 256
#define HID   128
#define BB    256
#define TT    512
#define G4    512        // gate columns per direction
#define GWH   1024       // f16 columns in EW2 ([dir][u][g] packed)

typedef _Float16 f16x8 __attribute__((ext_vector_type(8)));
typedef _Float16 f16x4 __attribute__((ext_vector_type(4)));
typedef float    f32x4 __attribute__((ext_vector_type(4)));

__device__ __forceinline__ float fexp2(float x){
#if __has_builtin(__builtin_amdgcn_exp2f)
  return __builtin_amdgcn_exp2f(x);
#else
  return exp2f(x);
#endif
}
__device__ __forceinline__ float frcp(float x){
#if __has_builtin(__builtin_amdgcn_rcpf)
  return __builtin_amdgcn_rcpf(x);
#else
  return 1.0f/x;
#endif
}
__device__ __forceinline__ float sigm(float x){
  return frcp(1.0f + fexp2(-1.4426950408889634f*x));
}
__device__ __forceinline__ float fast_tanh(float x){
  return 1.0f - 2.0f*frcp(1.0f + fexp2(2.8853900817779268f*x));
}

// ---------------------------------------------------------------------------
// Kernel 1: EW2[v][dirc*512 + u*4 + g] = f16( emb[v] @ Wcol(g*128+u) + b )
// Block: 64 vocab rows x (dirc, u-tile of 16) -> 64 original cols.
// Lane col cl -> (ul=cl>>2, g=cl&3): 16-lane store groups are 32B contiguous.
// ---------------------------------------------------------------------------
__global__ __launch_bounds__(256, 4) void embw_mfma(
    const float* __restrict__ emb,
    const float* __restrict__ Wf, const float* __restrict__ Wb,
    const float* __restrict__ bf, const float* __restrict__ bb,
    _Float16* __restrict__ EW)
{
  __shared__ _Float16 As[64*EMBED];   // 32 KB
  const int tid  = threadIdx.x;
  const int l    = tid & 63;
  const int w    = tid >> 6;
  const int r0   = blockIdx.x * 64;
  const int dirc = blockIdx.y >> 3;
  const int u0   = (blockIdx.y & 7) * 16;
  const int nr   = min(64, VOCAB - r0);

  const float4* asrc = (const float4*)(emb + (size_t)r0*EMBED);
  for (int i = tid; i < nr*(EMBED/4); i += 256){
    float4 v = asrc[i];
    const int row = i >> 6;
    const int kc  = (i & 63) * 4;
    const int ks  = kc ^ ((row & 7) << 3);
    _Float16* dst = &As[row*EMBED + ks];
    dst[0]=(_Float16)v.x; dst[1]=(_Float16)v.y;
    dst[2]=(_Float16)v.z; dst[3]=(_Float16)v.w;
  }
  __syncthreads();

  const int cl = w*16 + (l & 15);
  const int ul = cl >> 2;             // 0..15
  const int g  = cl & 3;              // gate
  const int cg = g*128 + u0 + ul;     // original column in [0,512)
  const float* Wsrc = (dirc ? Wb : Wf) + cg;
  const int kg = (l >> 4) * 8;

  f32x4 acc[4] = {{0,0,0,0},{0,0,0,0},{0,0,0,0},{0,0,0,0}};

  for (int kk = 0; kk < EMBED/32; ++kk){
    const int kb = kk*32 + kg;
    f16x8 bfrag;
    #pragma unroll
    for (int j = 0; j < 8; ++j)
      bfrag[j] = (_Float16)Wsrc[(size_t)(kb + j)*G4];
    #pragma unroll
    for (int m = 0; m < 4; ++m){
      const int row = m*16 + (l & 15);
      const int ks  = kb ^ ((row & 7) << 3);
      f16x8 afrag = *(const f16x8*)&As[row*EMBED + ks];
      acc[m] = __builtin_amdgcn_mfma_f32_16x16x32_f16(afrag, bfrag, acc[m], 0, 0, 0);
    }
  }

  const float bv = (dirc ? bb : bf)[cg];
  const int   co = dirc*512 + (u0 + ul)*4 + g;     // f16 col in EW2
  #pragma unroll
  for (int m = 0; m < 4; ++m){
    #pragma unroll
    for (int r = 0; r < 4; ++r){
      const int vrow = r0 + m*16 + (l >> 4)*4 + r;
      if (vrow < VOCAB)
        EW[(size_t)vrow*GWH + co] = (_Float16)(acc[m][r] + bv);
    }
  }
}

// ---------------------------------------------------------------------------
// Kernel 2: recurrence (round-8 structure + f16 packed xw, 2-deep prefetch,
// padded h buffer, split MFMA chains). Block = 2 batches x 1 dir, grid 256.
// ---------------------------------------------------------------------------
__global__ __launch_bounds__(512, 2) void lstm_r9(
    const int*      __restrict__ tokens,
    const _Float16* __restrict__ EW,
    const float*    __restrict__ Ufw, const float* __restrict__ Ubw,
    float* __restrict__ out)
{
  __shared__ _Float16 h_lds[2][320];   // batch0 @ f16 idx 0, batch1 @ 160 (pad)
  __shared__ int      tok_lds[2*TT];   // 4 KB

  const int tid = threadIdx.x;
  const int l   = tid & 63;
  const int w   = tid >> 6;               // wave 0..7
  const int lr  = l & 15;
  const int hi  = l >> 4;
  const int dir = blockIdx.x & 1;
  const int b0  = (blockIdx.x >> 1) * 2;

  if (tid < 640) ((_Float16*)h_lds)[tid] = (_Float16)0.f;
  for (int i = tid; i < 2*TT; i += 512)
    tok_lds[i] = tokens[(b0 + (i >> 9))*TT + (i & 511)];
  __syncthreads();

  // ---- resident U B-fragments: ub[kt][gate], 64 VGPRs ----
  const float* U = dir ? Ubw : Ufw;
  f16x8 ub[4][4];
  #pragma unroll
  for (int kt = 0; kt < 4; ++kt){
    #pragma unroll
    for (int g = 0; g < 4; ++g){
      const int col = g*128 + w*16 + lr;
      f16x8 f;
      #pragma unroll
      for (int j = 0; j < 8; ++j)
        f[j] = (_Float16)U[(size_t)(kt*32 + hi*8 + j)*G4 + col];
      ub[kt][g] = f;
    }
  }

  const int  bsel = (l >> 2) & 1;      // A-row -> batch
  const bool act  = (l < 32);
  const int  q    = hi & 1;            // batch (lanes 0-31); 32-63 mirror
  const int  u    = w*16 + lr;         // hidden unit

  float creg = 0.f, hfin = 0.f;
  const _Float16* ebase = EW + dir*512 + u*4;

  #define AADDR(S) ({ int ss_ = (S); ss_ = ss_ < TT ? ss_ : TT-1;            \
                      const int tt_ = dir ? (TT-1-ss_) : ss_;                \
                      ebase + (size_t)tok_lds[q*TT + tt_]*GWH; })

  f16x4 xwA = *(const f16x4*)AADDR(0);
  f16x4 xwB = *(const f16x4*)AADDR(1);
  const _Float16* adA = AADDR(2);
  const _Float16* adB = AADDR(3);

  #define STEP(XW, AD, SCUR, CUR)                                            \
  {                                                                          \
    const int t_ = dir ? (TT-1-(SCUR)) : (SCUR);                             \
    f16x8 ha[4];                                                             \
    _Pragma("unroll")                                                        \
    for (int kt = 0; kt < 4; ++kt)                                           \
      ha[kt] = *(const f16x8*)&h_lds[CUR][bsel*160 + kt*32 + hi*8];          \
    float cin[4];                                                            \
    _Pragma("unroll")                                                        \
    for (int g = 0; g < 4; ++g) cin[g] = (float)XW[g];                       \
    XW = *(const f16x4*)AD;            /* reload this slot for SCUR+2 */     \
    AD = AADDR((SCUR)+4);              /* address for the next reload */     \
    f32x4 aP[4], aQ[4];                                                      \
    _Pragma("unroll")                                                        \
    for (int g = 0; g < 4; ++g){                                             \
      aP[g] = (f32x4){cin[g], 0.f, 0.f, 0.f};                                \
      aQ[g] = (f32x4){0.f, 0.f, 0.f, 0.f};                                   \
    }                                                                        \
    _Pragma("unroll")                                                        \
    for (int g = 0; g < 4; ++g){                                             \
      aP[g] = __builtin_amdgcn_mfma_f32_16x16x32_f16(ha[0], ub[0][g], aP[g], 0,0,0); \
      aQ[g] = __builtin_amdgcn_mfma_f32_16x16x32_f16(ha[2], ub[2][g], aQ[g], 0,0,0); \
      aP[g] = __builtin_amdgcn_mfma_f32_16x16x32_f16(ha[1], ub[1][g], aP[g], 0,0,0); \
      aQ[g] = __builtin_amdgcn_mfma_f32_16x16x32_f16(ha[3], ub[3][g], aQ[g], 0,0,0); \
    }                                                                        \
    if (act){                                                                \
      const float zi = aP[0][0]+aQ[0][0], zf = aP[1][0]+aQ[1][0];            \
      const float zg = aP[2][0]+aQ[2][0], zo = aP[3][0]+aQ[3][0];            \
      const float cn = sigm(zf)*creg + sigm(zi)*fast_tanh(zg);               \
      creg = cn;                                                             \
      const float hh = sigm(zo)*fast_tanh(cn);                               \
      hfin = hh;                                                             \
      h_lds[(CUR)^1][q*160 + u] = (_Float16)hh;                              \
      out[((size_t)(b0+q)*TT + t_)*(2*HID) + (size_t)dir*HID + u] = hh;      \
    }                                                                        \
    asm volatile("s_waitcnt lgkmcnt(0)" ::: "memory");                       \
    __builtin_amdgcn_s_barrier();                                            \
  }

  for (int s = 0; s < TT; s += 2){
    STEP(xwA, adA, s,     0)
    STEP(xwB, adB, s + 1, 1)
  }
  #undef STEP
  #undef AADDR

  // ---- final h_T / c_T ----
  if (act){
    const size_t O1  = (size_t)BB*TT*(2*HID);
    const size_t idx = (size_t)(b0+q)*HID + u;
    if (dir == 0){
      out[O1                    + idx] = hfin;
      out[O1 +   (size_t)BB*HID + idx] = creg;
    } else {
      out[O1 + 2*(size_t)BB*HID + idx] = hfin;
      out[O1 + 3*(size_t)BB*HID + idx] = creg;
    }
  }
}

extern "C" void kernel_launch(void* const* d_in, const int* in_sizes, int n_in,
                              void* d_out, int out_size, void* d_ws, size_t ws_size,
                              hipStream_t stream)
{
  const int*   tokens = (const int*)  d_in[0];
  const float* emb    = (const float*)d_in[1];
  const float* Wf     = (const float*)d_in[2];
  const float* Ufw    = (const float*)d_in[3];
  const float* bf     = (const float*)d_in[4];
  const float* Wb     = (const float*)d_in[5];
  const float* Ubw    = (const float*)d_in[6];
  const float* bb     = (const float*)d_in[7];
  float* out = (float*)d_out;
  _Float16* EW = (_Float16*)d_ws;     // 30000 x 1024 f16 = 61.44 MB

  embw_mfma<<<dim3((VOCAB + 63)/64, 16), 256, 0, stream>>>(emb, Wf, Wb, bf, bb, EW);
  lstm_r9<<<BB, 512, 0, stream>>>(tokens, EW, Ufw, Ubw, out);
}

// Round 10
// 370.600 us; speedup vs baseline: 2.8036x; 1.0269x over previous
//
#include <hip/hip_runtime.h>
#include <hip/hip_bf16.h>
#include <stdint.h>

#define VOCAB 30000
#define EMBED 256
#define HID   128
#define BB    256
#define TT    512
#define G4    512        // gate columns per direction
#define GWH   1024       // f16 columns in EW2 ([dir][u][g] packed)

typedef _Float16 f16x8 __attribute__((ext_vector_type(8)));
typedef _Float16 f16x4 __attribute__((ext_vector_type(4)));
typedef float    f32x4 __attribute__((ext_vector_type(4)));

// gate scales folded into EW and U at build time:
//   i,f,o : z' = -log2(e)  * z   -> sigm = rcp(1 + exp2(z'))
//   g     : z' = +2log2(e) * z   -> tanh = 1 - 2*rcp(1 + exp2(z'))
#define S_IFO (-1.4426950408889634f)
#define S_G   ( 2.8853900817779268f)

__device__ __forceinline__ float fexp2(float x){
#if __has_builtin(__builtin_amdgcn_exp2f)
  return __builtin_amdgcn_exp2f(x);
#else
  return exp2f(x);
#endif
}
__device__ __forceinline__ float frcp(float x){
#if __has_builtin(__builtin_amdgcn_rcpf)
  return __builtin_amdgcn_rcpf(x);
#else
  return 1.0f/x;
#endif
}
__device__ __forceinline__ float sigm_p(float zp){          // zp pre-scaled
  return frcp(1.0f + fexp2(zp));
}
__device__ __forceinline__ float tanh_p(float zp){          // zp pre-scaled
  return 1.0f - 2.0f*frcp(1.0f + fexp2(zp));
}
__device__ __forceinline__ float tanh_rt(float x){          // runtime tanh
  return 1.0f - 2.0f*frcp(1.0f + fexp2(S_G*x));
}

// ---------------------------------------------------------------------------
// Kernel 1: EW2[v][dirc*512 + u*4 + g] = f16( gsc[g] * (emb[v]@Wcol + b) )
// ---------------------------------------------------------------------------
__global__ __launch_bounds__(256, 4) void embw_mfma(
    const float* __restrict__ emb,
    const float* __restrict__ Wf, const float* __restrict__ Wb,
    const float* __restrict__ bf, const float* __restrict__ bb,
    _Float16* __restrict__ EW)
{
  __shared__ _Float16 As[64*EMBED];   // 32 KB
  const int tid  = threadIdx.x;
  const int l    = tid & 63;
  const int w    = tid >> 6;
  const int r0   = blockIdx.x * 64;
  const int dirc = blockIdx.y >> 3;
  const int u0   = (blockIdx.y & 7) * 16;
  const int nr   = min(64, VOCAB - r0);

  const float4* asrc = (const float4*)(emb + (size_t)r0*EMBED);
  for (int i = tid; i < nr*(EMBED/4); i += 256){
    float4 v = asrc[i];
    const int row = i >> 6;
    const int kc  = (i & 63) * 4;
    const int ks  = kc ^ ((row & 7) << 3);
    _Float16* dst = &As[row*EMBED + ks];
    dst[0]=(_Float16)v.x; dst[1]=(_Float16)v.y;
    dst[2]=(_Float16)v.z; dst[3]=(_Float16)v.w;
  }
  __syncthreads();

  const int cl = w*16 + (l & 15);
  const int ul = cl >> 2;             // 0..15
  const int g  = cl & 3;              // gate
  const int cg = g*128 + u0 + ul;     // original column in [0,512)
  const float* Wsrc = (dirc ? Wb : Wf) + cg;
  const int kg = (l >> 4) * 8;

  f32x4 acc[4] = {{0,0,0,0},{0,0,0,0},{0,0,0,0},{0,0,0,0}};

  for (int kk = 0; kk < EMBED/32; ++kk){
    const int kb = kk*32 + kg;
    f16x8 bfrag;
    #pragma unroll
    for (int j = 0; j < 8; ++j)
      bfrag[j] = (_Float16)Wsrc[(size_t)(kb + j)*G4];
    #pragma unroll
    for (int m = 0; m < 4; ++m){
      const int row = m*16 + (l & 15);
      const int ks  = kb ^ ((row & 7) << 3);
      f16x8 afrag = *(const f16x8*)&As[row*EMBED + ks];
      acc[m] = __builtin_amdgcn_mfma_f32_16x16x32_f16(afrag, bfrag, acc[m], 0, 0, 0);
    }
  }

  const float bv  = (dirc ? bb : bf)[cg];
  const float gsc = (g == 2) ? S_G : S_IFO;
  const int   co  = dirc*512 + (u0 + ul)*4 + g;    // f16 col in EW2
  #pragma unroll
  for (int m = 0; m < 4; ++m){
    #pragma unroll
    for (int r = 0; r < 4; ++r){
      const int vrow = r0 + m*16 + (l >> 4)*4 + r;
      if (vrow < VOCAB)
        EW[(size_t)vrow*GWH + co] = (_Float16)((acc[m][r] + bv) * gsc);
    }
  }
}

// ---------------------------------------------------------------------------
// Kernel 2: recurrence. Round-9 structure + persistent accumulators (init
// once; garbage D-rows 1-3 never read, rows don't mix in MFMA) + pre-scaled
// activations (no runtime log2e muls). Block = 2 batches x 1 dir, grid 256.
// ---------------------------------------------------------------------------
__global__ __launch_bounds__(512, 2) void lstm_r10(
    const int*      __restrict__ tokens,
    const _Float16* __restrict__ EW,
    const float*    __restrict__ Ufw, const float* __restrict__ Ubw,
    float* __restrict__ out)
{
  __shared__ _Float16 h_lds[2][320];   // batch0 @ f16 idx 0, batch1 @ 160 (pad)
  __shared__ int      tok_lds[2*TT];   // 4 KB

  const int tid = threadIdx.x;
  const int l   = tid & 63;
  const int w   = tid >> 6;               // wave 0..7
  const int lr  = l & 15;
  const int hi  = l >> 4;
  const int dir = blockIdx.x & 1;
  const int b0  = (blockIdx.x >> 1) * 2;

  if (tid < 640) ((_Float16*)h_lds)[tid] = (_Float16)0.f;
  for (int i = tid; i < 2*TT; i += 512)
    tok_lds[i] = tokens[(b0 + (i >> 9))*TT + (i & 511)];
  __syncthreads();

  // ---- resident U B-fragments (pre-scaled): ub[kt][gate], 64 VGPRs ----
  const float* U = dir ? Ubw : Ufw;
  f16x8 ub[4][4];
  #pragma unroll
  for (int kt = 0; kt < 4; ++kt){
    #pragma unroll
    for (int g = 0; g < 4; ++g){
      const int   col = g*128 + w*16 + lr;
      const float gs  = (g == 2) ? S_G : S_IFO;
      f16x8 f;
      #pragma unroll
      for (int j = 0; j < 8; ++j)
        f[j] = (_Float16)(U[(size_t)(kt*32 + hi*8 + j)*G4 + col] * gs);
      ub[kt][g] = f;
    }
  }

  const int  bsel = (l >> 2) & 1;      // A-row -> batch
  const bool act  = (l < 32);
  const int  q    = hi & 1;            // batch (lanes 0-31); 32-63 mirror
  const int  u    = w*16 + lr;         // hidden unit

  float creg = 0.f, hfin = 0.f;
  const _Float16* ebase = EW + dir*512 + u*4;

  // persistent accumulators: rows 1-3 accumulate garbage, never read
  f32x4 aP[4];
  #pragma unroll
  for (int g = 0; g < 4; ++g) aP[g] = (f32x4){0.f,0.f,0.f,0.f};

  #define AADDR(S) ({ int ss_ = (S); ss_ = ss_ < TT ? ss_ : TT-1;            \
                      const int tt_ = dir ? (TT-1-ss_) : ss_;                \
                      ebase + (size_t)tok_lds[q*TT + tt_]*GWH; })

  f16x4 xwA = *(const f16x4*)AADDR(0);
  f16x4 xwB = *(const f16x4*)AADDR(1);
  const _Float16* adA = AADDR(2);
  const _Float16* adB = AADDR(3);

  #define STEP(XW, AD, SCUR, CUR)                                            \
  {                                                                          \
    const int t_ = dir ? (TT-1-(SCUR)) : (SCUR);                             \
    f16x8 ha[4];                                                             \
    _Pragma("unroll")                                                        \
    for (int kt = 0; kt < 4; ++kt)                                           \
      ha[kt] = *(const f16x8*)&h_lds[CUR][bsel*160 + kt*32 + hi*8];          \
    _Pragma("unroll")                                                        \
    for (int g = 0; g < 4; ++g) aP[g][0] = (float)XW[g];                     \
    XW = *(const f16x4*)AD;            /* reload this slot for SCUR+2 */     \
    AD = AADDR((SCUR)+4);              /* address for the next reload */     \
    _Pragma("unroll")                                                        \
    for (int kt = 0; kt < 4; ++kt){                                          \
      _Pragma("unroll")                                                      \
      for (int g = 0; g < 4; ++g)                                            \
        aP[g] = __builtin_amdgcn_mfma_f32_16x16x32_f16(ha[kt], ub[kt][g], aP[g], 0,0,0); \
    }                                                                        \
    if (act){                                                                \
      const float si = sigm_p(aP[0][0]);                                     \
      const float sf = sigm_p(aP[1][0]);                                     \
      const float tg = tanh_p(aP[2][0]);                                     \
      const float so = sigm_p(aP[3][0]);                                     \
      const float cn = sf*creg + si*tg;                                      \
      creg = cn;                                                             \
      const float hh = so*tanh_rt(cn);                                       \
      hfin = hh;                                                             \
      h_lds[(CUR)^1][q*160 + u] = (_Float16)hh;                              \
      out[((size_t)(b0+q)*TT + t_)*(2*HID) + (size_t)dir*HID + u] = hh;      \
    }                                                                        \
    asm volatile("s_waitcnt lgkmcnt(0)" ::: "memory");                       \
    __builtin_amdgcn_s_barrier();                                            \
  }

  for (int s = 0; s < TT; s += 2){
    STEP(xwA, adA, s,     0)
    STEP(xwB, adB, s + 1, 1)
  }
  #undef STEP
  #undef AADDR

  // ---- final h_T / c_T ----
  if (act){
    const size_t O1  = (size_t)BB*TT*(2*HID);
    const size_t idx = (size_t)(b0+q)*HID + u;
    if (dir == 0){
      out[O1                    + idx] = hfin;
      out[O1 +   (size_t)BB*HID + idx] = creg;
    } else {
      out[O1 + 2*(size_t)BB*HID + idx] = hfin;
      out[O1 + 3*(size_t)BB*HID + idx] = creg;
    }
  }
}

extern "C" void kernel_launch(void* const* d_in, const int* in_sizes, int n_in,
                              void* d_out, int out_size, void* d_ws, size_t ws_size,
                              hipStream_t stream)
{
  const int*   tokens = (const int*)  d_in[0];
  const float* emb    = (const float*)d_in[1];
  const float* Wf     = (const float*)d_in[2];
  const float* Ufw    = (const float*)d_in[3];
  const float* bf     = (const float*)d_in[4];
  const float* Wb     = (const float*)d_in[5];
  const float* Ubw    = (const float*)d_in[6];
  const float* bb     = (const float*)d_in[7];
  float* out = (float*)d_out;
  _Float16* EW = (_Float16*)d_ws;     // 30000 x 1024 f16 = 61.44 MB

  embw_mfma<<<dim3((VOCAB + 63)/64, 16), 256, 0, stream>>>(emb, Wf, Wb, bf, bb, EW);
  lstm_r10<<<BB, 512, 0, stream>>>(tokens, EW, Ufw, Ubw, out);
}